// Round 2
// baseline (1055.050 us; speedup 1.0000x reference)
//
#include <hip/hip_runtime.h>

#define NPTS 524288
#define NSEG 64
#define NBLK (NPTS / 64)      // 8192 blocks of 64 rows
#define MAXP (NBLK + NSEG)    // max part records (8256)

typedef __bf16 bf16x8 __attribute__((ext_vector_type(8)));
typedef float f32x4 __attribute__((ext_vector_type(4)));

__device__ __forceinline__ unsigned int f2bf(float f) {
  unsigned int u = __float_as_uint(f);
  return (u + 0x7FFFu + ((u >> 16) & 1u)) >> 16;  // RNE bf16
}

// Branchless erf, Abramowitz-Stegun 7.1.26, |err| <= 1.5e-7
__device__ __forceinline__ float gelu_f(float h) {
  const float u = 0.70710678118654752f * h;
  const float a = fabsf(u);
  const float t = __builtin_amdgcn_rcpf(fmaf(0.3275911f, a, 1.0f));
  const float e = __expf(-a * a);
  float p = fmaf(1.061405429f, t, -1.453152027f);
  p = fmaf(p, t, 1.421413741f);
  p = fmaf(p, t, -0.284496736f);
  p = fmaf(p, t, 0.254829592f);
  p *= t;
  const float erfa = fmaf(-p, e, 1.0f);
  const float erfu = copysignf(erfa, u);
  return 0.5f * h * (1.0f + erfu);
}

// ---------------- prep: w1 [512][256] f32 -> bf16 packed [(k>>3)][n][k&7] ----------------
__global__ void prep_w1(const float* __restrict__ w1, unsigned short* __restrict__ w1p) {
  int idx = blockIdx.x * 256 + threadIdx.x;   // 0..131071
  int k = idx >> 8, n = idx & 255;
  w1p[((k >> 3) << 11) + (n << 3) + (k & 7)] = (unsigned short)f2bf(w1[idx]);
}

// ---------------- fused: LN -> bf16 MFMA GEMM -> GELU -> s -> per-(block,seg) partial pool ----
// Block: 64 rows, 256 threads (4 waves). Emits partial records {seg, m_loc, z_loc, P[512]}.
__global__ __launch_bounds__(256, 2) void fused_kernel(
    const float* __restrict__ feats, const float* __restrict__ ln_w,
    const float* __restrict__ ln_b, const unsigned short* __restrict__ w1p,
    const float* __restrict__ b1, const float* __restrict__ w2,
    const float* __restrict__ b2, const int* __restrict__ offs,
    float* __restrict__ m_arr, float* __restrict__ z_arr,
    int* __restrict__ seg_arr, float* __restrict__ Pp) {
  __shared__ __align__(16) unsigned short xs[64 * 512];  // 64KB bf16 x-tile, XOR-swizzled
  __shared__ float sred[4][64];
  __shared__ float e_all[64];
  __shared__ float sh_m[64];
  __shared__ int sh_bound[66];
  __shared__ int sh_meta[3];  // nparts, part_base, seg0
  char* xsb = (char*)xs;
  const int tid = threadIdx.x;
  const int lane = tid & 63;
  const int wid = tid >> 6;
  const long row0 = (long)blockIdx.x * 64;

  // ---- part bookkeeping (thread 0; 63 iterations) ----
  if (tid == 0) {
    const int r0i = (int)row0;
    int ncut = 0, pbase = blockIdx.x, seg0 = 0;
    sh_bound[0] = 0;
    for (int j = 1; j < NSEG; ++j) {
      const int c = offs[j];
      if (c <= r0i) { ++seg0; if (c & 63) ++pbase; }
      else if (c < r0i + 64) { sh_bound[++ncut] = c - r0i; }
    }
    sh_bound[ncut + 1] = 64;
    sh_meta[0] = ncut + 1; sh_meta[1] = pbase; sh_meta[2] = seg0;
  }

  // ---- Phase 1: LayerNorm, one wave per 16 rows, write bf16 x to LDS ----
  const int c0 = lane * 4;
  const float4 lw0 = *(const float4*)(ln_w + c0);
  const float4 lw1 = *(const float4*)(ln_w + 256 + c0);
  const float4 lb0 = *(const float4*)(ln_b + c0);
  const float4 lb1 = *(const float4*)(ln_b + 256 + c0);

  #pragma unroll 4
  for (int rr = 0; rr < 16; ++rr) {
    const int row = wid * 16 + rr;
    const float* rp = feats + (row0 + row) * 512;
    const float4 v0 = *(const float4*)(rp + c0);
    const float4 v1 = *(const float4*)(rp + 256 + c0);
    float sum = (v0.x + v0.y) + (v0.z + v0.w) + (v1.x + v1.y) + (v1.z + v1.w);
    float sq  = v0.x * v0.x + v0.y * v0.y + v0.z * v0.z + v0.w * v0.w
              + v1.x * v1.x + v1.y * v1.y + v1.z * v1.z + v1.w * v1.w;
    #pragma unroll
    for (int off = 32; off >= 1; off >>= 1) {
      sum += __shfl_xor(sum, off);
      sq  += __shfl_xor(sq, off);
    }
    const float mean = sum * (1.0f / 512.0f);
    const float var  = sq * (1.0f / 512.0f) - mean * mean;
    const float rstd = rsqrtf(var + 1e-5f);
    const float x0 = (v0.x - mean) * rstd * lw0.x + lb0.x;
    const float x1 = (v0.y - mean) * rstd * lw0.y + lb0.y;
    const float x2 = (v0.z - mean) * rstd * lw0.z + lb0.z;
    const float x3 = (v0.w - mean) * rstd * lw0.w + lb0.w;
    const float y0 = (v1.x - mean) * rstd * lw1.x + lb1.x;
    const float y1 = (v1.y - mean) * rstd * lw1.y + lb1.y;
    const float y2 = (v1.z - mean) * rstd * lw1.z + lb1.z;
    const float y3 = (v1.w - mean) * rstd * lw1.w + lb1.w;
    const unsigned int p0 = f2bf(x0) | (f2bf(x1) << 16);
    const unsigned int p1 = f2bf(x2) | (f2bf(x3) << 16);
    const unsigned int p2 = f2bf(y0) | (f2bf(y1) << 16);
    const unsigned int p3 = f2bf(y2) | (f2bf(y3) << 16);
    const unsigned int a0 = ((unsigned int)(row * 1024 + c0 * 2)) ^ (((unsigned int)(row & 7)) << 4);
    const unsigned int a1 = ((unsigned int)(row * 1024 + 512 + c0 * 2)) ^ (((unsigned int)(row & 7)) << 4);
    *(uint2*)(xsb + a0) = make_uint2(p0, p1);
    *(uint2*)(xsb + a1) = make_uint2(p2, p3);
  }
  __syncthreads();

  // ---- Phase 2: GEMM  h[64x256] = x[64x512] @ w1 ----
  const int l15 = lane & 15, l4 = lane >> 4;
  const int nb = wid * 64;
  f32x4 acc[4][4];
  #pragma unroll
  for (int i = 0; i < 4; ++i)
    #pragma unroll
    for (int j = 0; j < 4; ++j)
      acc[i][j] = f32x4{0.f, 0.f, 0.f, 0.f};

  #pragma unroll 4
  for (int ks = 0; ks < 16; ++ks) {
    bf16x8 av[4], bv[4];
    #pragma unroll
    for (int mt = 0; mt < 4; ++mt) {
      const int row = mt * 16 + l15;
      const unsigned int ad =
          ((unsigned int)(row * 1024 + ks * 64 + l4 * 16)) ^ (((unsigned int)(row & 7)) << 4);
      av[mt] = *(const bf16x8*)(xsb + ad);
    }
    #pragma unroll
    for (int nt = 0; nt < 4; ++nt) {
      const int idx = (((ks * 4 + l4) << 8) + nb + nt * 16 + l15) << 3;
      bv[nt] = *(const bf16x8*)(w1p + idx);
    }
    #pragma unroll
    for (int mt = 0; mt < 4; ++mt)
      #pragma unroll
      for (int nt = 0; nt < 4; ++nt)
        acc[mt][nt] = __builtin_amdgcn_mfma_f32_16x16x32_bf16(av[mt], bv[nt], acc[mt][nt], 0, 0, 0);
  }

  // ---- Epilogue: s_row = sum_n gelu(acc + b1) * w2 ----
  float b1v[4], w2v[4];
  #pragma unroll
  for (int nt = 0; nt < 4; ++nt) {
    const int n = nb + nt * 16 + l15;
    b1v[nt] = b1[n];
    w2v[nt] = w2[n];
  }
  #pragma unroll
  for (int mt = 0; mt < 4; ++mt) {
    #pragma unroll
    for (int r = 0; r < 4; ++r) {
      float v = 0.0f;
      #pragma unroll
      for (int nt = 0; nt < 4; ++nt) {
        const float h = acc[mt][nt][r] + b1v[nt];
        v += gelu_f(h) * w2v[nt];
      }
      v += __shfl_xor(v, 1);
      v += __shfl_xor(v, 2);
      v += __shfl_xor(v, 4);
      v += __shfl_xor(v, 8);
      if (l15 == 0) sred[wid][mt * 16 + l4 * 4 + r] = v;
    }
  }
  __syncthreads();

  // ---- Phase 3 (wave 0): per-part m_loc, z_loc, e[row]; write headers ----
  if (wid == 0) {
    const int npart = sh_meta[0], pbase = sh_meta[1], seg0 = sh_meta[2];
    const float sv = sred[0][lane] + sred[1][lane] + sred[2][lane] + sred[3][lane] + b2[0];
    int pid = 0;
    for (int i = 1; i < npart; ++i) pid += (sh_bound[i] <= lane) ? 1 : 0;
    float mym = -INFINITY;
    for (int k = 0; k < npart; ++k) {
      float v = (pid == k) ? sv : -INFINITY;
      #pragma unroll
      for (int off = 32; off >= 1; off >>= 1) v = fmaxf(v, __shfl_xor(v, off));
      if (pid == k) mym = v;
      if (lane == 0) sh_m[k] = v;
    }
    const float e = __expf(sv - mym);
    e_all[lane] = e;
    for (int k = 0; k < npart; ++k) {
      float v = (pid == k) ? e : 0.0f;
      #pragma unroll
      for (int off = 32; off >= 1; off >>= 1) v += __shfl_xor(v, off);
      if (lane == 0) {
        m_arr[pbase + k] = sh_m[k];
        z_arr[pbase + k] = v;
        seg_arr[pbase + k] = seg0 + k;
      }
    }
  }
  __syncthreads();

  // ---- Phase 4: partial pool P[c] = sum_rows e[r] * feats[r][c]  (feats re-read, L2-hot) ----
  {
    const int pbase = sh_meta[1];
    const float2* f2p = (const float2*)feats + (size_t)row0 * 256;
    float2* Pp2 = (float2*)Pp;
    float2 pacc = make_float2(0.f, 0.f);
    int k = 0;
    #pragma unroll 4
    for (int r = 0; r < 64; ++r) {
      if (r == sh_bound[k + 1]) {
        Pp2[(size_t)(pbase + k) * 256 + tid] = pacc;
        pacc.x = 0.f; pacc.y = 0.f;
        ++k;
      }
      const float e = e_all[r];
      const float2 f = f2p[(size_t)r * 256 + tid];
      pacc.x += e * f.x;
      pacc.y += e * f.y;
    }
    Pp2[(size_t)(pbase + k) * 256 + tid] = pacc;
  }
}

// ---------------- combine: per segment, merge partials (exact two-level softmax) ----------------
__global__ __launch_bounds__(512) void combine_kernel(
    const int* __restrict__ offs, const float* __restrict__ m_arr,
    const float* __restrict__ z_arr, const int* __restrict__ seg_arr,
    const float* __restrict__ Pp, float* __restrict__ out) {
  const int b = blockIdx.x;
  const int tid = threadIdx.x;
  const int lane = tid & 63, wid = tid >> 6;
  __shared__ int s_lo, s_hi;
  __shared__ float red[8];
  __shared__ float s_MZ[2];

  int Ptot = NBLK;
  for (int j = 1; j < NSEG; ++j) Ptot += (offs[j] & 63) ? 1 : 0;

  if (tid == 0) { s_lo = 1 << 30; s_hi = -1; }
  __syncthreads();
  int llo = 1 << 30, lhi = -1;
  for (int p = tid; p < Ptot; p += 512) {
    if (seg_arr[p] == b) { llo = min(llo, p); lhi = max(lhi, p); }
  }
  atomicMin(&s_lo, llo);
  atomicMax(&s_hi, lhi);
  __syncthreads();
  const int lo = s_lo, hi = s_hi;  // parts of a segment are contiguous (row-ordered)

  float lm = -INFINITY;
  for (int p = lo + tid; p <= hi; p += 512) lm = fmaxf(lm, m_arr[p]);
  #pragma unroll
  for (int off = 32; off >= 1; off >>= 1) lm = fmaxf(lm, __shfl_xor(lm, off));
  if (lane == 0) red[wid] = lm;
  __syncthreads();
  if (tid == 0) {
    float M = red[0];
    for (int w = 1; w < 8; ++w) M = fmaxf(M, red[w]);
    float Z = 0.0f;
    for (int p = lo; p <= hi; ++p) Z += z_arr[p] * __expf(m_arr[p] - M);  // fixed order
    s_MZ[0] = M; s_MZ[1] = Z;
  }
  __syncthreads();
  const float M = s_MZ[0];
  const float invZ = 1.0f / s_MZ[1];
  float acc = 0.0f;
  for (int p = lo; p <= hi; ++p)
    acc += __expf(m_arr[p] - M) * Pp[(size_t)p * 512 + tid];  // fixed order, coalesced
  out[b * 512 + tid] = acc * invZ;
}

extern "C" void kernel_launch(void* const* d_in, const int* in_sizes, int n_in,
                              void* d_out, int out_size, void* d_ws, size_t ws_size,
                              hipStream_t stream) {
  const float* feats = (const float*)d_in[0];
  const float* ln_w  = (const float*)d_in[1];
  const float* ln_b  = (const float*)d_in[2];
  const float* w1    = (const float*)d_in[3];
  const float* b1    = (const float*)d_in[4];
  const float* w2    = (const float*)d_in[5];
  const float* b2    = (const float*)d_in[6];
  const int* offs    = (const int*)d_in[7];
  float* out = (float*)d_out;

  char* ws = (char*)d_ws;
  unsigned short* w1p = (unsigned short*)(ws);                 // 256 KB
  float* m_arr  = (float*)(ws + 262144);                       // MAXP floats
  float* z_arr  = (float*)(ws + 327680);
  int*   seg_arr= (int*)  (ws + 393216);
  float* Pp     = (float*)(ws + 524288);                       // MAXP * 512 f32 (~16.9 MB)

  prep_w1<<<512, 256, 0, stream>>>(w1, w1p);
  fused_kernel<<<NBLK, 256, 0, stream>>>(feats, ln_w, ln_b, w1p, b1, w2, b2, offs,
                                         m_arr, z_arr, seg_arr, Pp);
  combine_kernel<<<NSEG, 512, 0, stream>>>(offs, m_arr, z_arr, seg_arr, Pp, out);
}